// Round 1
// baseline (372.895 us; speedup 1.0000x reference)
//
#include <hip/hip_runtime.h>

// Problem shape (fixed by reference): segmentation [B=2, C=32, D=64, H=128, W=128] fp32
#define DD 64
#define HH 128
#define WW 128
#define BC 64      // B*C
#define HALF_D 32
#define NBINS 32

// ws layout (doubles):
//   [0..63]    crown sums per bc
//   [64..127]  root sums per bc
//   [128..159] gx partial bins
//   [160..191] gy partial bins
//   [192..223] gz partial bins
#define WS_DOUBLES 224

__global__ __launch_bounds__(256) void anatomy_main(const float* __restrict__ seg,
                                                    double* __restrict__ ws) {
    const int w4      = threadIdx.x & 31;   // float4 index along W (32*4 = 128)
    const int h_local = threadIdx.x >> 5;   // 0..7
    const int htile   = blockIdx.x;         // 0..15
    const int bc      = blockIdx.y;         // 0..63
    const int h       = htile * 8 + h_local;

    float crown = 0.f, root = 0.f, gx = 0.f, gy = 0.f, gz = 0.f;
    float4 prev = make_float4(0.f, 0.f, 0.f, 0.f);

    const size_t bcBase = (size_t)bc * DD * HH * WW;

    for (int d = 0; d < DD; ++d) {
        const float* row = seg + bcBase + ((size_t)d * HH + h) * WW;
        float4 v = ((const float4*)row)[w4];

        float s = v.x + v.y + v.z + v.w;
        if (d < HALF_D) crown += s; else root += s;

        // x-gradient: intra-float4 + seam to next lane's first element
        gx += fabsf(v.y - v.x) + fabsf(v.z - v.y) + fabsf(v.w - v.z);
        float nx = __shfl_down(v.x, 1);     // lanes 0..31 / 32..63 are same-h rows
        if (w4 < 31) gx += fabsf(nx - v.w);

        // y-gradient: neighbor row (mostly L1/L2 hits; sibling threads load it too)
        if (h + 1 < HH) {
            float4 n = ((const float4*)(row + WW))[w4];
            gy += fabsf(n.x - v.x) + fabsf(n.y - v.y) + fabsf(n.z - v.z) + fabsf(n.w - v.w);
        }

        // z-gradient: previous slice kept in registers
        if (d > 0) {
            gz += fabsf(v.x - prev.x) + fabsf(v.y - prev.y) +
                  fabsf(v.z - prev.z) + fabsf(v.w - prev.w);
        }
        prev = v;
    }

    // wave (64-lane) shuffle reduction
    #pragma unroll
    for (int o = 32; o; o >>= 1) {
        crown += __shfl_down(crown, o);
        root  += __shfl_down(root,  o);
        gx    += __shfl_down(gx,    o);
        gy    += __shfl_down(gy,    o);
        gz    += __shfl_down(gz,    o);
    }

    __shared__ float red[4][5];
    const int wave = threadIdx.x >> 6;
    const int lane = threadIdx.x & 63;
    if (lane == 0) {
        red[wave][0] = crown; red[wave][1] = root;
        red[wave][2] = gx;    red[wave][3] = gy; red[wave][4] = gz;
    }
    __syncthreads();
    if (threadIdx.x == 0) {
        float c = 0.f, r = 0.f, x = 0.f, y = 0.f, z = 0.f;
        #pragma unroll
        for (int i = 0; i < 4; ++i) {
            c += red[i][0]; r += red[i][1];
            x += red[i][2]; y += red[i][3]; z += red[i][4];
        }
        const int bin = (int)((blockIdx.y * gridDim.x + blockIdx.x) & (NBINS - 1));
        atomicAdd(&ws[bc],            (double)c);
        atomicAdd(&ws[64 + bc],       (double)r);
        atomicAdd(&ws[128 + bin],     (double)x);
        atomicAdd(&ws[160 + bin],     (double)y);
        atomicAdd(&ws[192 + bin],     (double)z);
    }
}

__global__ void anatomy_finalize(const double* __restrict__ ws, float* __restrict__ out) {
    const int t = threadIdx.x;  // 0..63, one wave

    // per-(b,c) ratio loss
    double crown = ws[t];
    double root  = ws[64 + t];
    double total = crown + root;
    double rl = 0.0;
    if (total > 0.0 && root > 0.0) {
        double r = crown / root - 1.2;
        rl = r * r;
    }
    // bin sums (32 bins each; lanes >= 32 contribute zero)
    double gx = (t < NBINS) ? ws[128 + t] : 0.0;
    double gy = (t < NBINS) ? ws[160 + t] : 0.0;
    double gz = (t < NBINS) ? ws[192 + t] : 0.0;

    #pragma unroll
    for (int o = 32; o; o >>= 1) {
        rl += __shfl_down(rl, o);
        gx += __shfl_down(gx, o);
        gy += __shfl_down(gy, o);
        gz += __shfl_down(gz, o);
    }

    if (t == 0) {
        const double n_gx = (double)BC * DD * HH * (WW - 1);   // 66,584,576
        const double n_gy = (double)BC * DD * (HH - 1) * WW;   // 66,584,576
        const double n_gz = (double)BC * (DD - 1) * HH * WW;   // 66,060,288
        double cr_loss    = (rl / (double)BC) * 2.0;           // CROWN_ROOT_W
        double tv         = gx / n_gx + gy / n_gy + gz / n_gz;
        double smooth     = tv * 1.5;                          // SMOOTH_W
        out[0] = (float)cr_loss;
        out[1] = (float)smooth;
        out[2] = (float)(cr_loss + smooth);
    }
}

extern "C" void kernel_launch(void* const* d_in, const int* in_sizes, int n_in,
                              void* d_out, int out_size, void* d_ws, size_t ws_size,
                              hipStream_t stream) {
    const float* seg = (const float*)d_in[0];
    float* out = (float*)d_out;
    double* ws = (double*)d_ws;

    hipMemsetAsync(d_ws, 0, WS_DOUBLES * sizeof(double), stream);

    dim3 grid(16, 64);   // 16 h-tiles x 64 (b,c) pairs = 1024 blocks
    anatomy_main<<<grid, 256, 0, stream>>>(seg, ws);
    anatomy_finalize<<<1, 64, 0, stream>>>(ws, out);
}

// Round 2
// 356.043 us; speedup vs baseline: 1.0473x; 1.0473x over previous
//
#include <hip/hip_runtime.h>

// Problem shape (fixed by reference): segmentation [B=2, C=32, D=64, H=128, W=128] fp32
#define DD 64
#define HH 128
#define WW 128
#define BC 64      // B*C
#define HALF_D 32
#define NBLK 1024  // 16 h-tiles * 64 bc

// ws layout (floats, SoA): ws[q*NBLK + bc*16 + htile], q = 0:crown 1:root 2:gx 3:gy 4:gz
// Every slot is written by exactly one block -> no zero-init, no atomics.

__global__ __launch_bounds__(256) void anatomy_main(const float* __restrict__ seg,
                                                    float* __restrict__ ws) {
    const int w4      = threadIdx.x & 31;   // float4 index along W (32*4 = 128)
    const int h_local = threadIdx.x >> 5;   // 0..7
    const int htile   = blockIdx.x;         // 0..15
    const int bc      = blockIdx.y;         // 0..63
    const int h       = htile * 8 + h_local;

    float crown = 0.f, root = 0.f, gx = 0.f, gy = 0.f, gz = 0.f;

    const float* p  = seg + (size_t)bc * DD * HH * WW + (size_t)h * WW + w4 * 4;
    // neighbor row: clamp at h==127 (loads own row -> diffs contribute exactly 0; L1 hit)
    const int nOff = (h == HH - 1) ? 0 : WW;

    float4 prev = make_float4(0.f, 0.f, 0.f, 0.f);

    for (int d = 0; d < DD; ++d) {
        float4 v = *(const float4*)p;
        float4 n = *(const float4*)(p + nOff);
        p += HH * WW;

        float s = v.x + v.y + v.z + v.w;
        if (d < HALF_D) crown += s; else root += s;

        // x-gradient: intra-float4 + seam to next lane's first element
        gx += fabsf(v.y - v.x) + fabsf(v.z - v.y) + fabsf(v.w - v.z);
        float nx = __shfl_down(v.x, 1);     // rows are 32-lane aligned
        if (w4 < 31) gx += fabsf(nx - v.w);

        // y-gradient (branch-free; h==127 contributes 0)
        gy += fabsf(n.x - v.x) + fabsf(n.y - v.y) + fabsf(n.z - v.z) + fabsf(n.w - v.w);

        // z-gradient: previous slice kept in registers
        if (d > 0) {
            gz += fabsf(v.x - prev.x) + fabsf(v.y - prev.y) +
                  fabsf(v.z - prev.z) + fabsf(v.w - prev.w);
        }
        prev = v;
    }

    // wave (64-lane) shuffle reduction
    #pragma unroll
    for (int o = 32; o; o >>= 1) {
        crown += __shfl_down(crown, o);
        root  += __shfl_down(root,  o);
        gx    += __shfl_down(gx,    o);
        gy    += __shfl_down(gy,    o);
        gz    += __shfl_down(gz,    o);
    }

    __shared__ float red[4][5];
    const int wave = threadIdx.x >> 6;
    const int lane = threadIdx.x & 63;
    if (lane == 0) {
        red[wave][0] = crown; red[wave][1] = root;
        red[wave][2] = gx;    red[wave][3] = gy; red[wave][4] = gz;
    }
    __syncthreads();
    if (threadIdx.x == 0) {
        float c = 0.f, r = 0.f, x = 0.f, y = 0.f, z = 0.f;
        #pragma unroll
        for (int i = 0; i < 4; ++i) {
            c += red[i][0]; r += red[i][1];
            x += red[i][2]; y += red[i][3]; z += red[i][4];
        }
        const int slot = bc * 16 + htile;
        ws[0 * NBLK + slot] = c;
        ws[1 * NBLK + slot] = r;
        ws[2 * NBLK + slot] = x;
        ws[3 * NBLK + slot] = y;
        ws[4 * NBLK + slot] = z;
    }
}

__global__ __launch_bounds__(256) void anatomy_finalize(const float* __restrict__ ws,
                                                        float* __restrict__ out) {
    const int t = threadIdx.x;  // 0..255

    // per-(b,c) ratio loss: lanes 0..63 each own one bc (16 slots)
    double rl = 0.0;
    if (t < BC) {
        double crown = 0.0, root = 0.0;
        #pragma unroll
        for (int i = 0; i < 16; ++i) {
            crown += (double)ws[0 * NBLK + t * 16 + i];
            root  += (double)ws[1 * NBLK + t * 16 + i];
        }
        double total = crown + root;
        if (total > 0.0 && root > 0.0) {
            double r = crown / root - 1.2;
            rl = r * r;
        }
    }

    // gradient sums: 1024 slots / 256 threads = 4 each
    double gx = 0.0, gy = 0.0, gz = 0.0;
    #pragma unroll
    for (int i = 0; i < 4; ++i) {
        gx += (double)ws[2 * NBLK + t * 4 + i];
        gy += (double)ws[3 * NBLK + t * 4 + i];
        gz += (double)ws[4 * NBLK + t * 4 + i];
    }

    // wave reduce
    #pragma unroll
    for (int o = 32; o; o >>= 1) {
        rl += __shfl_down(rl, o);
        gx += __shfl_down(gx, o);
        gy += __shfl_down(gy, o);
        gz += __shfl_down(gz, o);
    }

    __shared__ double red[4][4];
    const int wave = t >> 6;
    if ((t & 63) == 0) {
        red[wave][0] = rl; red[wave][1] = gx; red[wave][2] = gy; red[wave][3] = gz;
    }
    __syncthreads();
    if (t == 0) {
        double RL = 0, GX = 0, GY = 0, GZ = 0;
        #pragma unroll
        for (int i = 0; i < 4; ++i) {
            RL += red[i][0]; GX += red[i][1]; GY += red[i][2]; GZ += red[i][3];
        }
        const double n_gx = (double)BC * DD * HH * (WW - 1);
        const double n_gy = (double)BC * DD * (HH - 1) * WW;
        const double n_gz = (double)BC * (DD - 1) * HH * WW;
        double cr_loss = (RL / (double)BC) * 2.0;            // CROWN_ROOT_W
        double smooth  = (GX / n_gx + GY / n_gy + GZ / n_gz) * 1.5;  // SMOOTH_W
        out[0] = (float)cr_loss;
        out[1] = (float)smooth;
        out[2] = (float)(cr_loss + smooth);
    }
}

extern "C" void kernel_launch(void* const* d_in, const int* in_sizes, int n_in,
                              void* d_out, int out_size, void* d_ws, size_t ws_size,
                              hipStream_t stream) {
    const float* seg = (const float*)d_in[0];
    float* out = (float*)d_out;
    float* ws  = (float*)d_ws;

    dim3 grid(16, 64);   // 16 h-tiles x 64 (b,c) pairs = 1024 blocks
    anatomy_main<<<grid, 256, 0, stream>>>(seg, ws);
    anatomy_finalize<<<1, 256, 0, stream>>>(ws, out);
}